// Round 10
// baseline (148.645 us; speedup 1.0000x reference)
//
#include <hip/hip_runtime.h>
#include <hip/hip_fp16.h>
#include <hip/hip_bf16.h>
#include <cstddef>
#include <cstdint>

#define SNL_N 50000
#define SNL_K 32
#define SNL_D 128
#define SNL_EPS 1e-12f
#define ROWS_PB 25
#define NBLK 2000          // ~15KB LDS -> 8 blocks/CU (wave-capped) -> all co-resident
#define NPASS 8
#define BUCKET 6250        // fp16 bucket = 1.6 MB << 4 MiB L2/XCD  (r9's 12500 regressed)
#define NITEM (ROWS_PB * SNL_K)   // 800 items/block; code fits 10 bits
#define YIPAD 136          // yi LDS row pitch in halves
#define WS_NORM_OFF 16384
#define WS_GH_OFF (16384 + 204800)

// ---------------- fp16 quant + per-row norm pre-pass ------------------------
// One wave per 2 rows: lane = h*32 + c. Norms computed from the ROUNDED
// halves so d2 = ni + nj - 2*dot is consistent with the fp16 data.
// Also zeroes out[0] (harness poisons d_out before every launch) so the main
// kernel can accumulate the loss with atomicAdd -- no reduce kernel.
__global__ __launch_bounds__(256) void snl_quant(const float* __restrict__ emb,
                                                 __half* __restrict__ gh,
                                                 float* __restrict__ gnorm,
                                                 float* __restrict__ out) {
    if (blockIdx.x == 0 && threadIdx.x == 0) out[0] = 0.0f;
    const int tid  = threadIdx.x;
    const int lane = tid & 63;
    const int wid  = tid >> 6;
    const int h    = lane >> 5;
    const int c    = lane & 31;
    const int row  = (blockIdx.x * 4 + wid) * 2 + h;   // 6250 blocks x 8 rows
    const float4 v = reinterpret_cast<const float4*>(emb)[(size_t)row * 32 + c];
    __half2 h0 = __floats2half2_rn(v.x, v.y);
    __half2 h1 = __floats2half2_rn(v.z, v.w);
    uint2 pk;
    pk.x = *reinterpret_cast<unsigned int*>(&h0);
    pk.y = *reinterpret_cast<unsigned int*>(&h1);
    reinterpret_cast<uint2*>(gh)[(size_t)row * 32 + c] = pk;
    const float2 f0 = __half22float2(h0), f1 = __half22float2(h1);
    float nrm = f0.x * f0.x + f0.y * f0.y + f1.x * f1.x + f1.y * f1.y;
#pragma unroll
    for (int off = 1; off < 32; off <<= 1) nrm += __shfl_xor(nrm, off, 64);
    if (c == 0) gnorm[row] = nrm;
}

__device__ __forceinline__ float dot2acc(__half2 a, __half2 b, float c) {
#if __has_builtin(__builtin_amdgcn_fdot2)
    return __builtin_amdgcn_fdot2(a, b, c, false);
#else
    float2 fa = __half22float2(a), fb = __half22float2(b);
    c = fmaf(fa.x, fb.x, c);
    return fmaf(fa.y, fb.y, c);
#endif
}

// ---------------- main bucketed-pass kernel ---------------------------------
// EXACT r8 structure (47 us: 2000 co-resident blocks, NPASS=8 self-paced
// lockstep bucket passes, no software pipeline -- r9's NPASS=4 + pipeline
// both regressed) with only the norm-trick inner loop (8 fdot2, no hsub2)
// and atomic loss accumulation (reduce kernel removed).
__global__ __launch_bounds__(256, 8) void snl_main_h(
    const __half* __restrict__ gh,
    const float* __restrict__ gnorm,
    const float* __restrict__ psim,
    const int* __restrict__ aidx,
    float* __restrict__ out)
{
    const int tid = threadIdx.x;
    const int b   = blockIdx.x;
    const int i0  = b * ROWS_PB;

    __shared__ __half         yib[ROWS_PB * YIPAD];  // 6800 B
    __shared__ float          nib[ROWS_PB];          //  100 B
    __shared__ float          d2b[NITEM];            // 3200 B
    __shared__ unsigned short idb[NITEM];            // 1600 B
    __shared__ unsigned int   lst[NITEM];            // 3200 B: (a<<10)|(r*32+k)
    __shared__ int cnt[NPASS], offs[NPASS + 1], wrk[NPASS];
    __shared__ float bred[4];

    const float4* gh4 = reinterpret_cast<const float4*>(gh);  // 16B = 8 halves

    // ---- stage yi chunks + row norms + ids ----
    for (int it = 0; it < 2; ++it) {
        const int idx = it * 256 + tid;
        if (idx < ROWS_PB * 16) {
            const int row = idx >> 4, c = idx & 15;
            *reinterpret_cast<float4*>(&yib[row * YIPAD + c * 8]) =
                gh4[(size_t)(i0 + row) * 16 + c];
        }
    }
    if (tid < ROWS_PB) nib[tid] = gnorm[i0 + tid];
    for (int it = 0; it < 4; ++it) {
        const int idx = it * 256 + tid;
        if (idx < NITEM)
            idb[idx] = (unsigned short)aidx[(size_t)i0 * SNL_K + idx];
    }
    if (tid < NPASS) cnt[tid] = 0;
    __syncthreads();

    // ---- counting sort by bucket(anchor), anchor fused into entry ----
    for (int it = 0; it < 4; ++it) {
        const int idx = it * 256 + tid;
        if (idx < NITEM) atomicAdd(&cnt[idb[idx] / BUCKET], 1);
    }
    __syncthreads();
    if (tid == 0) {
        int acc = 0;
        for (int p = 0; p < NPASS; ++p) { offs[p] = acc; wrk[p] = acc; acc += cnt[p]; }
        offs[NPASS] = acc;
    }
    __syncthreads();
    for (int it = 0; it < 4; ++it) {
        const int idx = it * 256 + tid;
        if (idx < NITEM) {
            const unsigned a = idb[idx];
            lst[atomicAdd(&wrk[a / BUCKET], 1)] = (a << 10) | (unsigned)idx;
        }
    }
    __syncthreads();

    // ---- self-paced bucket passes ----
    const int oct  = tid >> 3;   // item slot in a 32-item step (0..31)
    const int dc   = tid & 7;    // 16B chunk; 8 lanes = one 256B fp16 row
    const int xsub = b >> 3;     // 0..249: slice within my XCD group (b%8 ~ XCD)
    float pf = 0.0f;

#pragma unroll 1
    for (int p = 0; p < NPASS; ++p) {
        // prefetch my XCD-group's 25-row slice of fp16 bucket p (400 chunks;
        // 250 blocks/XCD-group x 25 rows = 6250 = full bucket) + norm slice
        const int prow = p * BUCKET + xsub * ROWS_PB;
        const size_t pbase = (size_t)prow * 16;
        for (int it = 0; it < 2; ++it) {
            const int idx = it * 256 + tid;
            if (idx < ROWS_PB * 16) pf += gh4[pbase + idx].x;
        }
        if (tid < ROWS_PB) pf += gnorm[prow + tid];

        // dense processing of this block's in-bucket items
        const int s0 = offs[p], s1 = offs[p + 1];
        for (int base = s0; base < s1; base += 32) {
            const int item = base + oct;
            if (item < s1) {
                const unsigned e = lst[item];       // single dependent LDS read
                const int code = (int)(e & 1023u);
                const int r    = code >> 5;
                const int a    = (int)(e >> 10);
                const float4* jr = gh4 + (size_t)a * 16;
                const float njv = gnorm[a];         // broadcast L2 hit
                float acc = 0.0f;
#pragma unroll
                for (int it = 0; it < 2; ++it) {
                    float4 yjv = jr[dc + it * 8];   // bucket-p row -> L2 hit
                    float4 yiv = *reinterpret_cast<const float4*>(
                        &yib[r * YIPAD + (dc + it * 8) * 8]);
                    const __half2* hj = reinterpret_cast<const __half2*>(&yjv);
                    const __half2* hi = reinterpret_cast<const __half2*>(&yiv);
#pragma unroll
                    for (int u = 0; u < 4; ++u)
                        acc = dot2acc(hi[u], hj[u], acc);   // dot only (norm trick)
                }
                acc += __shfl_xor(acc, 1, 64);
                acc += __shfl_xor(acc, 2, 64);
                acc += __shfl_xor(acc, 4, 64);
                if (dc == 0) d2b[code] = nib[r] + njv - 2.0f * acc;
            }
        }
    }
    __syncthreads();

    // ---- softmax + outputs (one wave per row, round-robin) ----
    const int wid  = tid >> 6;
    const int lane = tid & 63;
    float loss_acc = 0.0f;
    for (int r = wid; r < ROWS_PB; r += 4) {
        const int i = i0 + r;
        const float d2 = d2b[r * SNL_K + (lane & 31)];
        const float s = -d2;
        float m = s;
#pragma unroll
        for (int off = 1; off < 32; off <<= 1)
            m = fmaxf(m, __shfl_xor(m, off, 64));
        const float e = __expf(s - m);
        float ss = e;
#pragma unroll
        for (int off = 1; off < 32; off <<= 1)
            ss += __shfl_xor(ss, off, 64);
        const float logq = (s - m) - __logf(ss);
        const float q = e / ss;
        if (lane < SNL_K) {
            out[1 + (size_t)i * SNL_K + lane] = q;
            const float pv = psim[(size_t)i * SNL_K + lane];
            loss_acc += pv * (__logf(pv + SNL_EPS) - logq);
        }
    }

    __asm__ volatile("" :: "v"(pf));   // keep prefetch loads alive

#pragma unroll
    for (int off = 1; off < 64; off <<= 1)
        loss_acc += __shfl_xor(loss_acc, off, 64);
    if (lane == 0) bred[wid] = loss_acc;
    __syncthreads();
    if (tid == 0)
        atomicAdd(out, (bred[0] + bred[1] + bred[2] + bred[3]) * (1.0f / SNL_N));
}

// ---------------- fallback: fp32 kernel (if ws too small) -------------------
#define F32_ROWS 50
#define F32_NBLK 1000
#define F32_NPASS 8
#define F32_BUCKET 6250
__global__ __launch_bounds__(256, 4) void snl_main_f32(
    const float* __restrict__ emb,
    const float* __restrict__ psim,
    const int* __restrict__ aidx,
    float* __restrict__ out,
    float* __restrict__ part)
{
    const int tid = threadIdx.x;
    const int b   = blockIdx.x;
    const int i0  = b * F32_ROWS;

    __shared__ float          yib[F32_ROWS * SNL_D];
    __shared__ float          d2b[F32_ROWS * SNL_K];
    __shared__ unsigned short idb[F32_ROWS * SNL_K];
    __shared__ unsigned short lst[F32_ROWS * SNL_K];
    __shared__ int cnt[F32_NPASS], offs[F32_NPASS + 1], wrk[F32_NPASS];
    __shared__ float bred[4];

    const float4* emb4 = reinterpret_cast<const float4*>(emb);

    for (int it = 0; it < 7; ++it) {
        const int idx = it * 256 + tid;
        if (idx < F32_ROWS * SNL_D / 4)
            reinterpret_cast<float4*>(yib)[idx] = emb4[(size_t)i0 * (SNL_D / 4) + idx];
        if (idx < F32_ROWS * SNL_K)
            idb[idx] = (unsigned short)aidx[(size_t)i0 * SNL_K + idx];
    }
    if (tid < F32_NPASS) cnt[tid] = 0;
    __syncthreads();
    for (int it = 0; it < 7; ++it) {
        const int idx = it * 256 + tid;
        if (idx < F32_ROWS * SNL_K) atomicAdd(&cnt[idb[idx] / F32_BUCKET], 1);
    }
    __syncthreads();
    if (tid == 0) {
        int acc = 0;
        for (int p = 0; p < F32_NPASS; ++p) { offs[p] = acc; wrk[p] = acc; acc += cnt[p]; }
        offs[F32_NPASS] = acc;
    }
    __syncthreads();
    for (int it = 0; it < 7; ++it) {
        const int idx = it * 256 + tid;
        if (idx < F32_ROWS * SNL_K) {
            const int p = idb[idx] / F32_BUCKET;
            lst[atomicAdd(&wrk[p], 1)] = (unsigned short)idx;
        }
    }
    __syncthreads();

    const int oct  = tid >> 3;
    const int dc   = tid & 7;
    const int xsub = b >> 3;
    float pf = 0.0f;

#pragma unroll 1
    for (int p = 0; p < F32_NPASS; ++p) {
        const size_t pbase4 = ((size_t)p * F32_BUCKET + (size_t)xsub * 50) * (SNL_D / 4);
        for (int it = 0; it < 7; ++it) {
            const int idx = it * 256 + tid;
            if (idx < 50 * SNL_D / 4) pf += emb4[pbase4 + idx].x;
        }
        const int s0 = offs[p], s1 = offs[p + 1];
        for (int base = s0; base < s1; base += 32) {
            const int item = base + oct;
            if (item < s1) {
                const int code = (int)lst[item];
                const int r = code >> 5;
                const int a = (int)idb[code];
                const float4* jr = emb4 + (size_t)a * (SNL_D / 4);
                float acc = 0.0f;
#pragma unroll
                for (int it = 0; it < 4; ++it) {
                    const float4 yj = jr[dc + it * 8];
                    const float4 yi =
                        reinterpret_cast<const float4*>(yib)[r * (SNL_D / 4) + dc + it * 8];
                    const float dx = yi.x - yj.x;
                    const float dy = yi.y - yj.y;
                    const float dz = yi.z - yj.z;
                    const float dw = yi.w - yj.w;
                    acc = fmaf(dx, dx, acc);
                    acc = fmaf(dy, dy, acc);
                    acc = fmaf(dz, dz, acc);
                    acc = fmaf(dw, dw, acc);
                }
                acc += __shfl_xor(acc, 1, 64);
                acc += __shfl_xor(acc, 2, 64);
                acc += __shfl_xor(acc, 4, 64);
                if (dc == 0) d2b[code] = acc;
            }
        }
    }
    __syncthreads();

    const int wid  = tid >> 6;
    const int lane = tid & 63;
    float loss_acc = 0.0f;
    for (int r = wid; r < F32_ROWS; r += 4) {
        const int i = i0 + r;
        const float d2 = d2b[r * SNL_K + (lane & 31)];
        const float s = -d2;
        float m = s;
#pragma unroll
        for (int off = 1; off < 32; off <<= 1)
            m = fmaxf(m, __shfl_xor(m, off, 64));
        const float e = __expf(s - m);
        float ss = e;
#pragma unroll
        for (int off = 1; off < 32; off <<= 1)
            ss += __shfl_xor(ss, off, 64);
        const float logq = (s - m) - __logf(ss);
        const float q = e / ss;
        if (lane < SNL_K) {
            out[1 + (size_t)i * SNL_K + lane] = q;
            const float pv = psim[(size_t)i * SNL_K + lane];
            loss_acc += pv * (__logf(pv + SNL_EPS) - logq);
        }
    }
    __asm__ volatile("" :: "v"(pf));
#pragma unroll
    for (int off = 1; off < 64; off <<= 1)
        loss_acc += __shfl_xor(loss_acc, off, 64);
    if (lane == 0) bred[wid] = loss_acc;
    __syncthreads();
    if (tid == 0) part[b] = bred[0] + bred[1] + bred[2] + bred[3];
}

__global__ __launch_bounds__(256) void snl_loss_reduce(const float* __restrict__ part,
                                                       int npart,
                                                       float* __restrict__ out) {
    double acc = 0.0;
    for (int i = threadIdx.x; i < npart; i += 256) acc += (double)part[i];
#pragma unroll
    for (int off = 1; off < 64; off <<= 1)
        acc += __shfl_xor(acc, off, 64);
    __shared__ double sred[4];
    if ((threadIdx.x & 63) == 0) sred[threadIdx.x >> 6] = acc;
    __syncthreads();
    if (threadIdx.x == 0)
        out[0] = (float)((sred[0] + sred[1] + sred[2] + sred[3]) / (double)SNL_N);
}

extern "C" void kernel_launch(void* const* d_in, const int* in_sizes, int n_in,
                              void* d_out, int out_size, void* d_ws, size_t ws_size,
                              hipStream_t stream) {
    const float* emb  = (const float*)d_in[0];
    const float* psim = (const float*)d_in[1];
    const int*   aidx = (const int*)d_in[2];
    float* out  = (float*)d_out;
    float* part = (float*)d_ws;   // first 8 KB (fallback partials)

    const size_t need = (size_t)WS_GH_OFF + (size_t)SNL_N * SNL_D * sizeof(__half);
    if (ws_size >= need) {
        float*  gnorm = (float*)((char*)d_ws + WS_NORM_OFF);
        __half* gh    = (__half*)((char*)d_ws + WS_GH_OFF);
        snl_quant<<<SNL_N / 8, 256, 0, stream>>>(emb, gh, gnorm, out);
        snl_main_h<<<NBLK, 256, 0, stream>>>(gh, gnorm, psim, aidx, out);
    } else {
        snl_main_f32<<<F32_NBLK, 256, 0, stream>>>(emb, psim, aidx, out, part);
        snl_loss_reduce<<<1, 256, 0, stream>>>(part, F32_NBLK, out);
    }
}

// Round 11
// 133.960 us; speedup vs baseline: 1.1096x; 1.1096x over previous
//
#include <hip/hip_runtime.h>
#include <hip/hip_fp16.h>
#include <hip/hip_bf16.h>
#include <cstddef>
#include <cstdint>

#define SNL_N 50000
#define SNL_K 32
#define SNL_D 128
#define SNL_EPS 1e-12f
#define ROWS_PB 25
#define NBLK 2000          // ~15KB LDS -> 8 blocks/CU (wave-capped) -> all co-resident
#define NPASS 8
#define BUCKET 6250        // fp16 bucket = 1.6 MB << 4 MiB L2/XCD
#define NITEM (ROWS_PB * SNL_K)   // 800 items/block; code fits 10 bits
#define YIPAD 136          // yi LDS row pitch in halves
#define WS_NORM_OFF 16384
#define WS_GH_OFF (16384 + 204800)

// ---------------- fp16 quant + per-row norm pre-pass ------------------------
// One wave per 2 rows: lane = h*32 + c. Norms computed from the ROUNDED
// halves so d2 = ni + nj - 2*dot is consistent with the fp16 data.
__global__ __launch_bounds__(256) void snl_quant(const float* __restrict__ emb,
                                                 __half* __restrict__ gh,
                                                 float* __restrict__ gnorm) {
    const int tid  = threadIdx.x;
    const int lane = tid & 63;
    const int wid  = tid >> 6;
    const int h    = lane >> 5;
    const int c    = lane & 31;
    const int row  = (blockIdx.x * 4 + wid) * 2 + h;   // 6250 blocks x 8 rows
    const float4 v = reinterpret_cast<const float4*>(emb)[(size_t)row * 32 + c];
    __half2 h0 = __floats2half2_rn(v.x, v.y);
    __half2 h1 = __floats2half2_rn(v.z, v.w);
    uint2 pk;
    pk.x = *reinterpret_cast<unsigned int*>(&h0);
    pk.y = *reinterpret_cast<unsigned int*>(&h1);
    reinterpret_cast<uint2*>(gh)[(size_t)row * 32 + c] = pk;
    const float2 f0 = __half22float2(h0), f1 = __half22float2(h1);
    float nrm = f0.x * f0.x + f0.y * f0.y + f1.x * f1.x + f1.y * f1.y;
#pragma unroll
    for (int off = 1; off < 32; off <<= 1) nrm += __shfl_xor(nrm, off, 64);
    if (c == 0) gnorm[row] = nrm;
}

__device__ __forceinline__ float dot2acc(__half2 a, __half2 b, float c) {
#if __has_builtin(__builtin_amdgcn_fdot2)
    return __builtin_amdgcn_fdot2(a, b, c, false);
#else
    float2 fa = __half22float2(a), fb = __half22float2(b);
    c = fmaf(fa.x, fb.x, c);
    return fmaf(fa.y, fb.y, c);
#endif
}

// ---------------- main bucketed-pass kernel ---------------------------------
// EXACT r8 structure (47 us: 2000 co-resident blocks, NPASS=8 self-paced
// lockstep bucket passes, part[]+reduce tail, NO atomics -- r10's 2000
// same-address atomicAdds are the suspected +25us idle tail). Only change
// vs r8: norm-trick inner loop (8 fdot2, no hsub2).
__global__ __launch_bounds__(256, 8) void snl_main_h(
    const __half* __restrict__ gh,
    const float* __restrict__ gnorm,
    const float* __restrict__ psim,
    const int* __restrict__ aidx,
    float* __restrict__ out,
    float* __restrict__ part)
{
    const int tid = threadIdx.x;
    const int b   = blockIdx.x;
    const int i0  = b * ROWS_PB;

    __shared__ __half         yib[ROWS_PB * YIPAD];  // 6800 B
    __shared__ float          nib[ROWS_PB];          //  100 B
    __shared__ float          d2b[NITEM];            // 3200 B
    __shared__ unsigned short idb[NITEM];            // 1600 B
    __shared__ unsigned int   lst[NITEM];            // 3200 B: (a<<10)|(r*32+k)
    __shared__ int cnt[NPASS], offs[NPASS + 1], wrk[NPASS];
    __shared__ float bred[4];

    const float4* gh4 = reinterpret_cast<const float4*>(gh);  // 16B = 8 halves

    // ---- stage yi chunks + row norms + ids ----
    for (int it = 0; it < 2; ++it) {
        const int idx = it * 256 + tid;
        if (idx < ROWS_PB * 16) {
            const int row = idx >> 4, c = idx & 15;
            *reinterpret_cast<float4*>(&yib[row * YIPAD + c * 8]) =
                gh4[(size_t)(i0 + row) * 16 + c];
        }
    }
    if (tid < ROWS_PB) nib[tid] = gnorm[i0 + tid];
    for (int it = 0; it < 4; ++it) {
        const int idx = it * 256 + tid;
        if (idx < NITEM)
            idb[idx] = (unsigned short)aidx[(size_t)i0 * SNL_K + idx];
    }
    if (tid < NPASS) cnt[tid] = 0;
    __syncthreads();

    // ---- counting sort by bucket(anchor), anchor fused into entry ----
    for (int it = 0; it < 4; ++it) {
        const int idx = it * 256 + tid;
        if (idx < NITEM) atomicAdd(&cnt[idb[idx] / BUCKET], 1);
    }
    __syncthreads();
    if (tid == 0) {
        int acc = 0;
        for (int p = 0; p < NPASS; ++p) { offs[p] = acc; wrk[p] = acc; acc += cnt[p]; }
        offs[NPASS] = acc;
    }
    __syncthreads();
    for (int it = 0; it < 4; ++it) {
        const int idx = it * 256 + tid;
        if (idx < NITEM) {
            const unsigned a = idb[idx];
            lst[atomicAdd(&wrk[a / BUCKET], 1)] = (a << 10) | (unsigned)idx;
        }
    }
    __syncthreads();

    // ---- self-paced bucket passes ----
    const int oct  = tid >> 3;   // item slot in a 32-item step (0..31)
    const int dc   = tid & 7;    // 16B chunk; 8 lanes = one 256B fp16 row
    const int xsub = b >> 3;     // 0..249: slice within my XCD group (b%8 ~ XCD)
    float pf = 0.0f;

#pragma unroll 1
    for (int p = 0; p < NPASS; ++p) {
        // prefetch my XCD-group's 25-row slice of fp16 bucket p (400 chunks;
        // 250 blocks/XCD-group x 25 rows = 6250 = full bucket) + norm slice
        const int prow = p * BUCKET + xsub * ROWS_PB;
        const size_t pbase = (size_t)prow * 16;
        for (int it = 0; it < 2; ++it) {
            const int idx = it * 256 + tid;
            if (idx < ROWS_PB * 16) pf += gh4[pbase + idx].x;
        }
        if (tid < ROWS_PB) pf += gnorm[prow + tid];

        // dense processing of this block's in-bucket items
        const int s0 = offs[p], s1 = offs[p + 1];
        for (int base = s0; base < s1; base += 32) {
            const int item = base + oct;
            if (item < s1) {
                const unsigned e = lst[item];       // single dependent LDS read
                const int code = (int)(e & 1023u);
                const int r    = code >> 5;
                const int a    = (int)(e >> 10);
                const float4* jr = gh4 + (size_t)a * 16;
                const float njv = gnorm[a];         // L1-resident 25KB slice
                float acc = 0.0f;
#pragma unroll
                for (int it = 0; it < 2; ++it) {
                    float4 yjv = jr[dc + it * 8];   // bucket-p row -> L2 hit
                    float4 yiv = *reinterpret_cast<const float4*>(
                        &yib[r * YIPAD + (dc + it * 8) * 8]);
                    const __half2* hj = reinterpret_cast<const __half2*>(&yjv);
                    const __half2* hi = reinterpret_cast<const __half2*>(&yiv);
#pragma unroll
                    for (int u = 0; u < 4; ++u)
                        acc = dot2acc(hi[u], hj[u], acc);   // dot only (norm trick)
                }
                acc += __shfl_xor(acc, 1, 64);
                acc += __shfl_xor(acc, 2, 64);
                acc += __shfl_xor(acc, 4, 64);
                if (dc == 0) d2b[code] = nib[r] + njv - 2.0f * acc;
            }
        }
    }
    __syncthreads();

    // ---- softmax + outputs (one wave per row, round-robin) ----
    const int wid  = tid >> 6;
    const int lane = tid & 63;
    float loss_acc = 0.0f;
    for (int r = wid; r < ROWS_PB; r += 4) {
        const int i = i0 + r;
        const float d2 = d2b[r * SNL_K + (lane & 31)];
        const float s = -d2;
        float m = s;
#pragma unroll
        for (int off = 1; off < 32; off <<= 1)
            m = fmaxf(m, __shfl_xor(m, off, 64));
        const float e = __expf(s - m);
        float ss = e;
#pragma unroll
        for (int off = 1; off < 32; off <<= 1)
            ss += __shfl_xor(ss, off, 64);
        const float logq = (s - m) - __logf(ss);
        const float q = e / ss;
        if (lane < SNL_K) {
            out[1 + (size_t)i * SNL_K + lane] = q;
            const float pv = psim[(size_t)i * SNL_K + lane];
            loss_acc += pv * (__logf(pv + SNL_EPS) - logq);
        }
    }

    __asm__ volatile("" :: "v"(pf));   // keep prefetch loads alive

#pragma unroll
    for (int off = 1; off < 64; off <<= 1)
        loss_acc += __shfl_xor(loss_acc, off, 64);
    if (lane == 0) bred[wid] = loss_acc;
    __syncthreads();
    if (tid == 0) part[b] = bred[0] + bred[1] + bred[2] + bred[3];
}

// ---------------- fallback: fp32 kernel (if ws too small) -------------------
#define F32_ROWS 50
#define F32_NBLK 1000
#define F32_NPASS 8
#define F32_BUCKET 6250
__global__ __launch_bounds__(256, 4) void snl_main_f32(
    const float* __restrict__ emb,
    const float* __restrict__ psim,
    const int* __restrict__ aidx,
    float* __restrict__ out,
    float* __restrict__ part)
{
    const int tid = threadIdx.x;
    const int b   = blockIdx.x;
    const int i0  = b * F32_ROWS;

    __shared__ float          yib[F32_ROWS * SNL_D];
    __shared__ float          d2b[F32_ROWS * SNL_K];
    __shared__ unsigned short idb[F32_ROWS * SNL_K];
    __shared__ unsigned short lst[F32_ROWS * SNL_K];
    __shared__ int cnt[F32_NPASS], offs[F32_NPASS + 1], wrk[F32_NPASS];
    __shared__ float bred[4];

    const float4* emb4 = reinterpret_cast<const float4*>(emb);

    for (int it = 0; it < 7; ++it) {
        const int idx = it * 256 + tid;
        if (idx < F32_ROWS * SNL_D / 4)
            reinterpret_cast<float4*>(yib)[idx] = emb4[(size_t)i0 * (SNL_D / 4) + idx];
        if (idx < F32_ROWS * SNL_K)
            idb[idx] = (unsigned short)aidx[(size_t)i0 * SNL_K + idx];
    }
    if (tid < F32_NPASS) cnt[tid] = 0;
    __syncthreads();
    for (int it = 0; it < 7; ++it) {
        const int idx = it * 256 + tid;
        if (idx < F32_ROWS * SNL_K) atomicAdd(&cnt[idb[idx] / F32_BUCKET], 1);
    }
    __syncthreads();
    if (tid == 0) {
        int acc = 0;
        for (int p = 0; p < F32_NPASS; ++p) { offs[p] = acc; wrk[p] = acc; acc += cnt[p]; }
        offs[F32_NPASS] = acc;
    }
    __syncthreads();
    for (int it = 0; it < 7; ++it) {
        const int idx = it * 256 + tid;
        if (idx < F32_ROWS * SNL_K) {
            const int p = idb[idx] / F32_BUCKET;
            lst[atomicAdd(&wrk[p], 1)] = (unsigned short)idx;
        }
    }
    __syncthreads();

    const int oct  = tid >> 3;
    const int dc   = tid & 7;
    const int xsub = b >> 3;
    float pf = 0.0f;

#pragma unroll 1
    for (int p = 0; p < F32_NPASS; ++p) {
        const size_t pbase4 = ((size_t)p * F32_BUCKET + (size_t)xsub * 50) * (SNL_D / 4);
        for (int it = 0; it < 7; ++it) {
            const int idx = it * 256 + tid;
            if (idx < 50 * SNL_D / 4) pf += emb4[pbase4 + idx].x;
        }
        const int s0 = offs[p], s1 = offs[p + 1];
        for (int base = s0; base < s1; base += 32) {
            const int item = base + oct;
            if (item < s1) {
                const int code = (int)lst[item];
                const int r = code >> 5;
                const int a = (int)idb[code];
                const float4* jr = emb4 + (size_t)a * (SNL_D / 4);
                float acc = 0.0f;
#pragma unroll
                for (int it = 0; it < 4; ++it) {
                    const float4 yj = jr[dc + it * 8];
                    const float4 yi =
                        reinterpret_cast<const float4*>(yib)[r * (SNL_D / 4) + dc + it * 8];
                    const float dx = yi.x - yj.x;
                    const float dy = yi.y - yj.y;
                    const float dz = yi.z - yj.z;
                    const float dw = yi.w - yj.w;
                    acc = fmaf(dx, dx, acc);
                    acc = fmaf(dy, dy, acc);
                    acc = fmaf(dz, dz, acc);
                    acc = fmaf(dw, dw, acc);
                }
                acc += __shfl_xor(acc, 1, 64);
                acc += __shfl_xor(acc, 2, 64);
                acc += __shfl_xor(acc, 4, 64);
                if (dc == 0) d2b[code] = acc;
            }
        }
    }
    __syncthreads();

    const int wid  = tid >> 6;
    const int lane = tid & 63;
    float loss_acc = 0.0f;
    for (int r = wid; r < F32_ROWS; r += 4) {
        const int i = i0 + r;
        const float d2 = d2b[r * SNL_K + (lane & 31)];
        const float s = -d2;
        float m = s;
#pragma unroll
        for (int off = 1; off < 32; off <<= 1)
            m = fmaxf(m, __shfl_xor(m, off, 64));
        const float e = __expf(s - m);
        float ss = e;
#pragma unroll
        for (int off = 1; off < 32; off <<= 1)
            ss += __shfl_xor(ss, off, 64);
        const float logq = (s - m) - __logf(ss);
        const float q = e / ss;
        if (lane < SNL_K) {
            out[1 + (size_t)i * SNL_K + lane] = q;
            const float pv = psim[(size_t)i * SNL_K + lane];
            loss_acc += pv * (__logf(pv + SNL_EPS) - logq);
        }
    }
    __asm__ volatile("" :: "v"(pf));
#pragma unroll
    for (int off = 1; off < 64; off <<= 1)
        loss_acc += __shfl_xor(loss_acc, off, 64);
    if (lane == 0) bred[wid] = loss_acc;
    __syncthreads();
    if (tid == 0) part[b] = bred[0] + bred[1] + bred[2] + bred[3];
}

__global__ __launch_bounds__(256) void snl_loss_reduce(const float* __restrict__ part,
                                                       int npart,
                                                       float* __restrict__ out) {
    double acc = 0.0;
    for (int i = threadIdx.x; i < npart; i += 256) acc += (double)part[i];
#pragma unroll
    for (int off = 1; off < 64; off <<= 1)
        acc += __shfl_xor(acc, off, 64);
    __shared__ double sred[4];
    if ((threadIdx.x & 63) == 0) sred[threadIdx.x >> 6] = acc;
    __syncthreads();
    if (threadIdx.x == 0)
        out[0] = (float)((sred[0] + sred[1] + sred[2] + sred[3]) / (double)SNL_N);
}

extern "C" void kernel_launch(void* const* d_in, const int* in_sizes, int n_in,
                              void* d_out, int out_size, void* d_ws, size_t ws_size,
                              hipStream_t stream) {
    const float* emb  = (const float*)d_in[0];
    const float* psim = (const float*)d_in[1];
    const int*   aidx = (const int*)d_in[2];
    float* out  = (float*)d_out;
    float* part = (float*)d_ws;   // first 8 KB (NBLK floats)

    const size_t need = (size_t)WS_GH_OFF + (size_t)SNL_N * SNL_D * sizeof(__half);
    if (ws_size >= need) {
        float*  gnorm = (float*)((char*)d_ws + WS_NORM_OFF);
        __half* gh    = (__half*)((char*)d_ws + WS_GH_OFF);
        snl_quant<<<SNL_N / 8, 256, 0, stream>>>(emb, gh, gnorm);
        snl_main_h<<<NBLK, 256, 0, stream>>>(gh, gnorm, psim, aidx, out, part);
        snl_loss_reduce<<<1, 256, 0, stream>>>(part, NBLK, out);
    } else {
        snl_main_f32<<<F32_NBLK, 256, 0, stream>>>(emb, psim, aidx, out, part);
        snl_loss_reduce<<<1, 256, 0, stream>>>(part, F32_NBLK, out);
    }
}

// Round 12
// 123.350 us; speedup vs baseline: 1.2051x; 1.0860x over previous
//
#include <hip/hip_runtime.h>
#include <hip/hip_fp16.h>
#include <hip/hip_bf16.h>
#include <cstddef>
#include <cstdint>

#define SNL_N 50000
#define SNL_K 32
#define SNL_D 128
#define SNL_EPS 1e-12f
#define ROWS_PB 25
#define NBLK 2000          // ~15KB LDS -> 8 blocks/CU (wave-capped) -> all co-resident
#define NPASS 8
#define BUCKET 6250        // fp16 bucket = 1.6 MB << 4 MiB L2/XCD
#define NITEM (ROWS_PB * SNL_K)   // 800 items/block; code fits 10 bits
#define YIPAD 136          // yi LDS row pitch in halves
#define WS_FP16_OFF 16384

// ---------------- fp16 quantization pre-pass (25.6 MB -> 12.8 MB) ----------
__global__ __launch_bounds__(256) void snl_quant(const float* __restrict__ emb,
                                                 __half* __restrict__ gh) {
    const int total = SNL_N * SNL_D / 4;   // float4 items
    for (int idx = blockIdx.x * 256 + threadIdx.x; idx < total; idx += gridDim.x * 256) {
        const float4 v = reinterpret_cast<const float4*>(emb)[idx];
        __half2 h0 = __floats2half2_rn(v.x, v.y);
        __half2 h1 = __floats2half2_rn(v.z, v.w);
        uint2 pk;
        pk.x = *reinterpret_cast<unsigned int*>(&h0);
        pk.y = *reinterpret_cast<unsigned int*>(&h1);
        reinterpret_cast<uint2*>(gh)[idx] = pk;
    }
}

__device__ __forceinline__ float dot2acc(__half2 a, __half2 b, float c) {
#if __has_builtin(__builtin_amdgcn_fdot2)
    return __builtin_amdgcn_fdot2(a, b, c, false);
#else
    float2 fa = __half22float2(a), fb = __half22float2(b);
    c = fmaf(fa.x, fb.x, c);
    return fmaf(fa.y, fb.y, c);
#endif
}

__device__ __forceinline__ float snl_dot16(const float4& yiv0, const float4& yiv1,
                                           const float4& yjv0, const float4& yjv1) {
    float acc = 0.0f;
    const __half2* hi0 = reinterpret_cast<const __half2*>(&yiv0);
    const __half2* hj0 = reinterpret_cast<const __half2*>(&yjv0);
    const __half2* hi1 = reinterpret_cast<const __half2*>(&yiv1);
    const __half2* hj1 = reinterpret_cast<const __half2*>(&yjv1);
#pragma unroll
    for (int u = 0; u < 4; ++u) {
        const __half2 d = __hsub2(hi0[u], hj0[u]);
        acc = dot2acc(d, d, acc);
    }
#pragma unroll
    for (int u = 0; u < 4; ++u) {
        const __half2 d = __hsub2(hi1[u], hj1[u]);
        acc = dot2acc(d, d, acc);
    }
    return acc;
}

// ---------------- main bucketed-pass kernel ---------------------------------
// EXACT r8 structure (47 us best: 2000 co-resident blocks, NPASS=8 self-paced
// lockstep bucket passes, hsub2+fdot2 inner loop, part[]+reduce tail -- r9-r11
// falsified NPASS=4, the clamped pipeline, the gnorm trick, and the atomic
// tail). Single change: item loop unrolled x2 -- full 64-item steps with no
// predication (both items' 4 global + 4 LDS float4 loads issued back-to-back,
// 2x chain-level MLP) plus the old 32-item predicated tail.
__global__ __launch_bounds__(256, 8) void snl_main_h(
    const __half* __restrict__ gh,
    const float* __restrict__ psim,
    const int* __restrict__ aidx,
    float* __restrict__ out,
    float* __restrict__ part)
{
    const int tid = threadIdx.x;
    const int b   = blockIdx.x;
    const int i0  = b * ROWS_PB;

    __shared__ __half         yib[ROWS_PB * YIPAD];  // 6800 B
    __shared__ float          d2b[NITEM];            // 3200 B
    __shared__ unsigned short idb[NITEM];            // 1600 B
    __shared__ unsigned int   lst[NITEM];            // 3200 B: (a<<10)|(r*32+k)
    __shared__ int cnt[NPASS], offs[NPASS + 1], wrk[NPASS];
    __shared__ float bred[4];

    const float4* gh4 = reinterpret_cast<const float4*>(gh);  // 16B = 8 halves

    // ---- stage yi (400 x 16B chunks) + ids (800) ----
    for (int it = 0; it < 2; ++it) {
        const int idx = it * 256 + tid;
        if (idx < ROWS_PB * 16) {
            const int row = idx >> 4, c = idx & 15;
            *reinterpret_cast<float4*>(&yib[row * YIPAD + c * 8]) =
                gh4[(size_t)(i0 + row) * 16 + c];
        }
    }
    for (int it = 0; it < 4; ++it) {
        const int idx = it * 256 + tid;
        if (idx < NITEM)
            idb[idx] = (unsigned short)aidx[(size_t)i0 * SNL_K + idx];
    }
    if (tid < NPASS) cnt[tid] = 0;
    __syncthreads();

    // ---- counting sort of (r,k) by bucket(anchor), anchor fused in entry ----
    for (int it = 0; it < 4; ++it) {
        const int idx = it * 256 + tid;
        if (idx < NITEM) atomicAdd(&cnt[idb[idx] / BUCKET], 1);
    }
    __syncthreads();
    if (tid == 0) {
        int acc = 0;
        for (int p = 0; p < NPASS; ++p) { offs[p] = acc; wrk[p] = acc; acc += cnt[p]; }
        offs[NPASS] = acc;
    }
    __syncthreads();
    for (int it = 0; it < 4; ++it) {
        const int idx = it * 256 + tid;
        if (idx < NITEM) {
            const unsigned a = idb[idx];
            lst[atomicAdd(&wrk[a / BUCKET], 1)] = (a << 10) | (unsigned)idx;
        }
    }
    __syncthreads();

    // ---- self-paced bucket passes ----
    const int oct  = tid >> 3;   // item slot in a 32-item step (0..31)
    const int dc   = tid & 7;    // 16B chunk; 8 lanes = one 256B fp16 row
    const int xsub = b >> 3;     // 0..249: slice within my XCD group (b%8 ~ XCD)
    float pf = 0.0f;

#pragma unroll 1
    for (int p = 0; p < NPASS; ++p) {
        // prefetch my XCD-group's 25-row slice of fp16 bucket p (400 chunks;
        // 250 blocks/XCD-group x 25 rows = 6250 = full bucket)
        const size_t pbase = ((size_t)p * BUCKET + (size_t)xsub * ROWS_PB) * 16;
        for (int it = 0; it < 2; ++it) {
            const int idx = it * 256 + tid;
            if (idx < ROWS_PB * 16) pf += gh4[pbase + idx].x;
        }

        // dense processing: full 64-item steps (no predication), then tail
        const int s0 = offs[p], s1 = offs[p + 1];
        const int nfull = (s1 - s0) & ~63;
        int base = s0;
#pragma unroll 1
        for (; base < s0 + nfull; base += 64) {
            const unsigned e0 = lst[base + oct];
            const unsigned e1 = lst[base + 32 + oct];
            const int code0 = (int)(e0 & 1023u), r0 = code0 >> 5, a0 = (int)(e0 >> 10);
            const int code1 = (int)(e1 & 1023u), r1 = code1 >> 5, a1 = (int)(e1 >> 10);
            const float4* jr0 = gh4 + (size_t)a0 * 16;
            const float4* jr1 = gh4 + (size_t)a1 * 16;
            const float4 gj00 = jr0[dc], gj01 = jr0[dc + 8];
            const float4 gj10 = jr1[dc], gj11 = jr1[dc + 8];
            const float4 yi00 = *reinterpret_cast<const float4*>(&yib[r0 * YIPAD + dc * 8]);
            const float4 yi01 = *reinterpret_cast<const float4*>(&yib[r0 * YIPAD + (dc + 8) * 8]);
            const float4 yi10 = *reinterpret_cast<const float4*>(&yib[r1 * YIPAD + dc * 8]);
            const float4 yi11 = *reinterpret_cast<const float4*>(&yib[r1 * YIPAD + (dc + 8) * 8]);
            float acc0 = snl_dot16(yi00, yi01, gj00, gj01);
            float acc1 = snl_dot16(yi10, yi11, gj10, gj11);
            acc0 += __shfl_xor(acc0, 1, 64);
            acc1 += __shfl_xor(acc1, 1, 64);
            acc0 += __shfl_xor(acc0, 2, 64);
            acc1 += __shfl_xor(acc1, 2, 64);
            acc0 += __shfl_xor(acc0, 4, 64);
            acc1 += __shfl_xor(acc1, 4, 64);
            if (dc == 0) {
                d2b[code0] = acc0;
                d2b[code1] = acc1;
            }
        }
#pragma unroll 1
        for (; base < s1; base += 32) {
            const int item = base + oct;
            if (item < s1) {
                const unsigned e = lst[item];
                const int code = (int)(e & 1023u);
                const int r    = code >> 5;
                const int a    = (int)(e >> 10);
                const float4* jr = gh4 + (size_t)a * 16;
                const float4 gj0 = jr[dc], gj1 = jr[dc + 8];
                const float4 yi0 = *reinterpret_cast<const float4*>(&yib[r * YIPAD + dc * 8]);
                const float4 yi1 = *reinterpret_cast<const float4*>(&yib[r * YIPAD + (dc + 8) * 8]);
                float acc = snl_dot16(yi0, yi1, gj0, gj1);
                acc += __shfl_xor(acc, 1, 64);
                acc += __shfl_xor(acc, 2, 64);
                acc += __shfl_xor(acc, 4, 64);
                if (dc == 0) d2b[code] = acc;
            }
        }
    }
    __syncthreads();

    // ---- softmax + outputs (one wave per row, round-robin) ----
    const int wid  = tid >> 6;
    const int lane = tid & 63;
    float loss_acc = 0.0f;
    for (int r = wid; r < ROWS_PB; r += 4) {
        const int i = i0 + r;
        const float d2 = d2b[r * SNL_K + (lane & 31)];
        const float s = -d2;
        float m = s;
#pragma unroll
        for (int off = 1; off < 32; off <<= 1)
            m = fmaxf(m, __shfl_xor(m, off, 64));
        const float e = __expf(s - m);
        float ss = e;
#pragma unroll
        for (int off = 1; off < 32; off <<= 1)
            ss += __shfl_xor(ss, off, 64);
        const float logq = (s - m) - __logf(ss);
        const float q = e / ss;
        if (lane < SNL_K) {
            out[1 + (size_t)i * SNL_K + lane] = q;
            const float pv = psim[(size_t)i * SNL_K + lane];
            loss_acc += pv * (__logf(pv + SNL_EPS) - logq);
        }
    }

    __asm__ volatile("" :: "v"(pf));   // keep prefetch loads alive

#pragma unroll
    for (int off = 1; off < 64; off <<= 1)
        loss_acc += __shfl_xor(loss_acc, off, 64);
    if (lane == 0) bred[wid] = loss_acc;
    __syncthreads();
    if (tid == 0) part[b] = bred[0] + bred[1] + bred[2] + bred[3];
}

// ---------------- fallback: fp32 kernel (if ws too small) -------------------
#define F32_ROWS 50
#define F32_NBLK 1000
#define F32_NPASS 8
#define F32_BUCKET 6250
__global__ __launch_bounds__(256, 4) void snl_main_f32(
    const float* __restrict__ emb,
    const float* __restrict__ psim,
    const int* __restrict__ aidx,
    float* __restrict__ out,
    float* __restrict__ part)
{
    const int tid = threadIdx.x;
    const int b   = blockIdx.x;
    const int i0  = b * F32_ROWS;

    __shared__ float          yib[F32_ROWS * SNL_D];
    __shared__ float          d2b[F32_ROWS * SNL_K];
    __shared__ unsigned short idb[F32_ROWS * SNL_K];
    __shared__ unsigned short lst[F32_ROWS * SNL_K];
    __shared__ int cnt[F32_NPASS], offs[F32_NPASS + 1], wrk[F32_NPASS];
    __shared__ float bred[4];

    const float4* emb4 = reinterpret_cast<const float4*>(emb);

    for (int it = 0; it < 7; ++it) {
        const int idx = it * 256 + tid;
        if (idx < F32_ROWS * SNL_D / 4)
            reinterpret_cast<float4*>(yib)[idx] = emb4[(size_t)i0 * (SNL_D / 4) + idx];
        if (idx < F32_ROWS * SNL_K)
            idb[idx] = (unsigned short)aidx[(size_t)i0 * SNL_K + idx];
    }
    if (tid < F32_NPASS) cnt[tid] = 0;
    __syncthreads();
    for (int it = 0; it < 7; ++it) {
        const int idx = it * 256 + tid;
        if (idx < F32_ROWS * SNL_K) atomicAdd(&cnt[idb[idx] / F32_BUCKET], 1);
    }
    __syncthreads();
    if (tid == 0) {
        int acc = 0;
        for (int p = 0; p < F32_NPASS; ++p) { offs[p] = acc; wrk[p] = acc; acc += cnt[p]; }
        offs[F32_NPASS] = acc;
    }
    __syncthreads();
    for (int it = 0; it < 7; ++it) {
        const int idx = it * 256 + tid;
        if (idx < F32_ROWS * SNL_K) {
            const int p = idb[idx] / F32_BUCKET;
            lst[atomicAdd(&wrk[p], 1)] = (unsigned short)idx;
        }
    }
    __syncthreads();

    const int oct  = tid >> 3;
    const int dc   = tid & 7;
    const int xsub = b >> 3;
    float pf = 0.0f;

#pragma unroll 1
    for (int p = 0; p < F32_NPASS; ++p) {
        const size_t pbase4 = ((size_t)p * F32_BUCKET + (size_t)xsub * 50) * (SNL_D / 4);
        for (int it = 0; it < 7; ++it) {
            const int idx = it * 256 + tid;
            if (idx < 50 * SNL_D / 4) pf += emb4[pbase4 + idx].x;
        }
        const int s0 = offs[p], s1 = offs[p + 1];
        for (int base = s0; base < s1; base += 32) {
            const int item = base + oct;
            if (item < s1) {
                const int code = (int)lst[item];
                const int r = code >> 5;
                const int a = (int)idb[code];
                const float4* jr = emb4 + (size_t)a * (SNL_D / 4);
                float acc = 0.0f;
#pragma unroll
                for (int it = 0; it < 4; ++it) {
                    const float4 yj = jr[dc + it * 8];
                    const float4 yi =
                        reinterpret_cast<const float4*>(yib)[r * (SNL_D / 4) + dc + it * 8];
                    const float dx = yi.x - yj.x;
                    const float dy = yi.y - yj.y;
                    const float dz = yi.z - yj.z;
                    const float dw = yi.w - yj.w;
                    acc = fmaf(dx, dx, acc);
                    acc = fmaf(dy, dy, acc);
                    acc = fmaf(dz, dz, acc);
                    acc = fmaf(dw, dw, acc);
                }
                acc += __shfl_xor(acc, 1, 64);
                acc += __shfl_xor(acc, 2, 64);
                acc += __shfl_xor(acc, 4, 64);
                if (dc == 0) d2b[code] = acc;
            }
        }
    }
    __syncthreads();

    const int wid  = tid >> 6;
    const int lane = tid & 63;
    float loss_acc = 0.0f;
    for (int r = wid; r < F32_ROWS; r += 4) {
        const int i = i0 + r;
        const float d2 = d2b[r * SNL_K + (lane & 31)];
        const float s = -d2;
        float m = s;
#pragma unroll
        for (int off = 1; off < 32; off <<= 1)
            m = fmaxf(m, __shfl_xor(m, off, 64));
        const float e = __expf(s - m);
        float ss = e;
#pragma unroll
        for (int off = 1; off < 32; off <<= 1)
            ss += __shfl_xor(ss, off, 64);
        const float logq = (s - m) - __logf(ss);
        const float q = e / ss;
        if (lane < SNL_K) {
            out[1 + (size_t)i * SNL_K + lane] = q;
            const float pv = psim[(size_t)i * SNL_K + lane];
            loss_acc += pv * (__logf(pv + SNL_EPS) - logq);
        }
    }
    __asm__ volatile("" :: "v"(pf));
#pragma unroll
    for (int off = 1; off < 64; off <<= 1)
        loss_acc += __shfl_xor(loss_acc, off, 64);
    if (lane == 0) bred[wid] = loss_acc;
    __syncthreads();
    if (tid == 0) part[b] = bred[0] + bred[1] + bred[2] + bred[3];
}

__global__ __launch_bounds__(256) void snl_loss_reduce(const float* __restrict__ part,
                                                       int npart,
                                                       float* __restrict__ out) {
    double acc = 0.0;
    for (int i = threadIdx.x; i < npart; i += 256) acc += (double)part[i];
#pragma unroll
    for (int off = 1; off < 64; off <<= 1)
        acc += __shfl_xor(acc, off, 64);
    __shared__ double sred[4];
    if ((threadIdx.x & 63) == 0) sred[threadIdx.x >> 6] = acc;
    __syncthreads();
    if (threadIdx.x == 0)
        out[0] = (float)((sred[0] + sred[1] + sred[2] + sred[3]) / (double)SNL_N);
}

extern "C" void kernel_launch(void* const* d_in, const int* in_sizes, int n_in,
                              void* d_out, int out_size, void* d_ws, size_t ws_size,
                              hipStream_t stream) {
    const float* emb  = (const float*)d_in[0];
    const float* psim = (const float*)d_in[1];
    const int*   aidx = (const int*)d_in[2];
    float* out  = (float*)d_out;
    float* part = (float*)d_ws;   // first 8 KB (NBLK floats)

    const size_t need = (size_t)WS_FP16_OFF + (size_t)SNL_N * SNL_D * sizeof(__half);
    if (ws_size >= need) {
        __half* gh = (__half*)((char*)d_ws + WS_FP16_OFF);
        snl_quant<<<2048, 256, 0, stream>>>(emb, gh);
        snl_main_h<<<NBLK, 256, 0, stream>>>(gh, psim, aidx, out, part);
        snl_loss_reduce<<<1, 256, 0, stream>>>(part, NBLK, out);
    } else {
        snl_main_f32<<<F32_NBLK, 256, 0, stream>>>(emb, psim, aidx, out, part);
        snl_loss_reduce<<<1, 256, 0, stream>>>(part, F32_NBLK, out);
    }
}